// Round 1
// baseline (374.110 us; speedup 1.0000x reference)
//
#include <hip/hip_runtime.h>
#include <math.h>

#define NN     16384
#define EE     600000
#define HIDN   128
#define NFT    32
#define NGAUSS 50
#define NLAY   6
#define TABN   8192
#define CUTF   10.0f

__device__ __forceinline__ float ssp(float x) {
    // softplus(x) - log(2), numerically stable
    return fmaxf(x, 0.0f) + log1pf(__expf(-fabsf(x))) - 0.69314718055994531f;
}

// ---------------------------------------------------------------- find ne ---
// mask = [1]*ne + [0]*(E-ne), monotone. Binary search first 0.
__global__ void find_ne(const float* __restrict__ mask, int* __restrict__ ne) {
    int lo = 0, hi = EE;
    while (lo < hi) {
        int mid = (lo + hi) >> 1;
        if (mask[mid] > 0.5f) lo = mid + 1; else hi = mid;
    }
    *ne = lo;
}

// ---------------------------------------------------------------- row_ptr ---
// dst sorted ascending over the first ne edges. rp[n] = lower_bound(dst, n).
__global__ void build_rowptr(const int* __restrict__ dst, const int* __restrict__ nep,
                             int* __restrict__ rp) {
    int n = blockIdx.x * blockDim.x + threadIdx.x;
    if (n > NN) return;
    int ne = *nep;
    if (n == NN) { rp[NN] = ne; return; }
    int lo = 0, hi = ne;
    while (lo < hi) {
        int mid = (lo + hi) >> 1;
        if (dst[mid] < n) lo = mid + 1; else hi = mid;
    }
    rp[n] = lo;
}

// ------------------------------------------------------------- edge geom ----
__global__ void edge_geom(const int* __restrict__ ei, const float* __restrict__ pos,
                          const float* __restrict__ mask,
                          float* __restrict__ de, float* __restrict__ ce) {
    int e = blockIdx.x * blockDim.x + threadIdx.x;
    if (e >= EE) return;
    int s = ei[e], t = ei[EE + e];
    float dx = pos[s * 3 + 0] - pos[t * 3 + 0];
    float dy = pos[s * 3 + 1] - pos[t * 3 + 1];
    float dz = pos[s * 3 + 2] - pos[t * 3 + 2];
    float d = sqrtf(dx * dx + dy * dy + dz * dz);
    de[e] = d;
    ce[e] = 0.5f * (cosf(d * 0.31415926535897932f) + 1.0f) * mask[e];
}

// ----------------------------------------------------------- table build ----
// tab[l][ent][f] = ( ssp(ea(d_ent) @ w1[l] + b1[l]) @ w2[l] + b2[l] )[f]
__global__ void tab_kernel(const float* __restrict__ w1, const float* __restrict__ b1,
                           const float* __restrict__ w2, const float* __restrict__ b2,
                           float* __restrict__ tab) {
    __shared__ float ea[8][NGAUSS];
    __shared__ float t1[8][NFT];
    int t = threadIdx.x, f = t & 31, g = t >> 5;
    int id = blockIdx.x * 8 + g;           // 0 .. NLAY*TABN-1 exact
    int l = id / TABN, ent = id % TABN;
    float d = ent * (CUTF / (TABN - 1));
    const float delta = CUTF / (NGAUSS - 1);
    const float coeff = -0.5f / (delta * delta);
    for (int gg = f; gg < NGAUSS; gg += 32) {
        float diff = d - gg * delta;
        ea[g][gg] = __expf(coeff * diff * diff);
    }
    __syncthreads();
    float a = b1[l * NFT + f];
    const float* w1l = w1 + l * NGAUSS * NFT;
    #pragma unroll
    for (int gg = 0; gg < NGAUSS; ++gg)
        a = fmaf(ea[g][gg], w1l[gg * NFT + f], a);
    t1[g][f] = ssp(a);
    __syncthreads();
    float c = b2[l * NFT + f];
    const float* w2l = w2 + l * NFT * NFT;
    #pragma unroll
    for (int k = 0; k < NFT; ++k)
        c = fmaf(t1[g][k], w2l[k * NFT + f], c);
    tab[(size_t)id * NFT + f] = c;
}

// ---------------------------------------------------------------- init h ----
__global__ void init_h(const int* __restrict__ z, const float4* __restrict__ emb4,
                       float4* __restrict__ h4) {
    int tid = blockIdx.x * blockDim.x + threadIdx.x;   // N*32 threads
    int n = tid >> 5, c = tid & 31;
    h4[tid] = emb4[(size_t)z[n] * 32 + c];
}

// ------------------------------------------------------------- hw = h@l1 ----
__global__ void hw_kernel(const float* __restrict__ h, const float* __restrict__ l1,
                          float* __restrict__ hw) {
    __shared__ float l1s[HIDN * NFT];
    int t = threadIdx.x, f = t & 31, nl = t >> 5;
    for (int i = t; i < HIDN * NFT / 4; i += 256)
        ((float4*)l1s)[i] = ((const float4*)l1)[i];
    __syncthreads();
    int n = blockIdx.x * 8 + nl;
    const float4* h4 = (const float4*)(h + (size_t)n * HIDN);
    float acc = 0.0f;
    #pragma unroll
    for (int k4 = 0; k4 < 32; ++k4) {
        float4 hv = h4[k4];
        acc = fmaf(hv.x, l1s[(k4 * 4 + 0) * NFT + f], acc);
        acc = fmaf(hv.y, l1s[(k4 * 4 + 1) * NFT + f], acc);
        acc = fmaf(hv.z, l1s[(k4 * 4 + 2) * NFT + f], acc);
        acc = fmaf(hv.w, l1s[(k4 * 4 + 3) * NFT + f], acc);
    }
    hw[(size_t)n * NFT + f] = acc;
}

// -------------------------------------------------- edge aggregate (CSR) ----
// 32 lanes per dst node; lane f owns feature f. No atomics.
__global__ void edge_agg(const int* __restrict__ rp, const int* __restrict__ src,
                         const float* __restrict__ de, const float* __restrict__ ce,
                         const float* __restrict__ tabL, const float* __restrict__ hw,
                         float* __restrict__ m) {
    int t = threadIdx.x, f = t & 31, g = t >> 5;
    int n = blockIdx.x * 8 + g;
    int r0 = rp[n], r1 = rp[n + 1];
    const float TS = (TABN - 1) / CUTF;
    float acc = 0.0f;
    for (int e = r0; e < r1; ++e) {
        int s = src[e];
        float d = de[e];
        float cc = ce[e];
        float p = d * TS;
        int i0 = (int)p;
        i0 = (i0 > TABN - 2) ? (TABN - 2) : i0;
        float fr = p - (float)i0;
        float w0 = tabL[(size_t)i0 * NFT + f];
        float w1v = tabL[(size_t)i0 * NFT + NFT + f];
        float w = fmaf(fr, w1v - w0, w0);
        acc = fmaf(hw[(size_t)s * NFT + f], w * cc, acc);
    }
    m[(size_t)n * NFT + f] = acc;
}

// ------------------------------------------- node update (two fused GEMMs) --
// x = ssp(m @ l2w + l2b);  h += x @ lw + lb
// 64 nodes/block, 512 threads, 4x4 register micro-tile, all operands in LDS.
#define FMA_ROW(acc, xv, wv)              \
    acc[0] = fmaf(xv, wv.x, acc[0]);      \
    acc[1] = fmaf(xv, wv.y, acc[1]);      \
    acc[2] = fmaf(xv, wv.z, acc[2]);      \
    acc[3] = fmaf(xv, wv.w, acc[3]);

__global__ __launch_bounds__(512) void node_update(
        const float* __restrict__ mg, const float* __restrict__ l2w,
        const float* __restrict__ l2b, const float* __restrict__ lwg,
        const float* __restrict__ lb, float* __restrict__ h) {
    extern __shared__ float sm[];
    float* l2ws = sm;                       // 32*128 = 4096
    float* lws  = sm + 4096;                // 128*128 = 16384
    float* xs   = sm + 4096 + 16384;        // 64*128 = 8192
    float* ms   = xs + 8192;                // 64*32 = 2048
    float* l2bs = ms + 2048;                // 128
    float* lbs  = l2bs + 128;               // 128

    const int t  = threadIdx.x;
    const int n0 = (t >> 5) << 2;           // 0..60
    const int f0 = (t & 31) << 2;           // 0..124
    const int nb = blockIdx.x << 6;

    for (int i = t; i < 1024; i += 512) ((float4*)l2ws)[i] = ((const float4*)l2w)[i];
    for (int i = t; i < 4096; i += 512) ((float4*)lws)[i]  = ((const float4*)lwg)[i];
    { int i = t; if (i < 512) ((float4*)ms)[i] = ((const float4*)(mg + (size_t)nb * NFT))[i]; }
    if (t < 128) { l2bs[t] = l2b[t]; lbs[t] = lb[t]; }
    __syncthreads();

    // phase A: a = m @ l2w + l2b  (K = 32)
    float a[4][4];
    #pragma unroll
    for (int i = 0; i < 4; ++i) {
        a[i][0] = l2bs[f0 + 0]; a[i][1] = l2bs[f0 + 1];
        a[i][2] = l2bs[f0 + 2]; a[i][3] = l2bs[f0 + 3];
    }
    #pragma unroll
    for (int k = 0; k < 32; k += 4) {
        float4 w0 = *(const float4*)(l2ws + (k + 0) * HIDN + f0);
        float4 w1 = *(const float4*)(l2ws + (k + 1) * HIDN + f0);
        float4 w2 = *(const float4*)(l2ws + (k + 2) * HIDN + f0);
        float4 w3 = *(const float4*)(l2ws + (k + 3) * HIDN + f0);
        #pragma unroll
        for (int i = 0; i < 4; ++i) {
            float4 mv = *(const float4*)(ms + (n0 + i) * NFT + k);
            FMA_ROW(a[i], mv.x, w0);
            FMA_ROW(a[i], mv.y, w1);
            FMA_ROW(a[i], mv.z, w2);
            FMA_ROW(a[i], mv.w, w3);
        }
    }
    #pragma unroll
    for (int i = 0; i < 4; ++i) {
        float4 xv;
        xv.x = ssp(a[i][0]); xv.y = ssp(a[i][1]);
        xv.z = ssp(a[i][2]); xv.w = ssp(a[i][3]);
        *(float4*)(xs + (n0 + i) * HIDN + f0) = xv;
    }
    __syncthreads();

    // phase B: b = x @ lw + lb  (K = 128); h += b
    float b[4][4];
    #pragma unroll
    for (int i = 0; i < 4; ++i) {
        b[i][0] = lbs[f0 + 0]; b[i][1] = lbs[f0 + 1];
        b[i][2] = lbs[f0 + 2]; b[i][3] = lbs[f0 + 3];
    }
    #pragma unroll 4
    for (int j = 0; j < 128; j += 4) {
        float4 w0 = *(const float4*)(lws + (j + 0) * HIDN + f0);
        float4 w1 = *(const float4*)(lws + (j + 1) * HIDN + f0);
        float4 w2 = *(const float4*)(lws + (j + 2) * HIDN + f0);
        float4 w3 = *(const float4*)(lws + (j + 3) * HIDN + f0);
        #pragma unroll
        for (int i = 0; i < 4; ++i) {
            float4 xv = *(const float4*)(xs + (n0 + i) * HIDN + j);
            FMA_ROW(b[i], xv.x, w0);
            FMA_ROW(b[i], xv.y, w1);
            FMA_ROW(b[i], xv.z, w2);
            FMA_ROW(b[i], xv.w, w3);
        }
    }
    #pragma unroll
    for (int i = 0; i < 4; ++i) {
        float* hp = h + (size_t)(nb + n0 + i) * HIDN + f0;
        float4 hv = *(float4*)hp;
        hv.x += b[i][0]; hv.y += b[i][1]; hv.z += b[i][2]; hv.w += b[i][3];
        *(float4*)hp = hv;
    }
}

// ---------------------------------------------------------------------------
extern "C" void kernel_launch(void* const* d_in, const int* in_sizes, int n_in,
                              void* d_out, int out_size, void* d_ws, size_t ws_size,
                              hipStream_t stream) {
    const int*   z    = (const int*)d_in[0];
    const float* pos  = (const float*)d_in[1];
    const int*   ei   = (const int*)d_in[2];    // [2][E]
    const float* mask = (const float*)d_in[3];
    const float* emb  = (const float*)d_in[4];
    const float* w1   = (const float*)d_in[5];  // [6][50][32]
    const float* b1   = (const float*)d_in[6];  // [6][32]
    const float* w2   = (const float*)d_in[7];  // [6][32][32]
    const float* b2   = (const float*)d_in[8];  // [6][32]
    const float* l1w  = (const float*)d_in[9];  // [6][128][32]
    const float* l2w  = (const float*)d_in[10]; // [6][32][128]
    const float* l2b  = (const float*)d_in[11]; // [6][128]
    const float* lww  = (const float*)d_in[12]; // [6][128][128]
    const float* lbb  = (const float*)d_in[13]; // [6][128]
    float* h = (float*)d_out;

    char* base = (char*)d_ws;
    size_t o = 0;
    auto alloc = [&](size_t bytes) -> void* {
        void* p = base + o;
        o += (bytes + 255) & ~(size_t)255;
        return p;
    };
    int*   d_ne  = (int*)alloc(sizeof(int));
    int*   d_rp  = (int*)alloc((NN + 1) * sizeof(int));
    float* d_de  = (float*)alloc((size_t)EE * sizeof(float));
    float* d_ce  = (float*)alloc((size_t)EE * sizeof(float));
    float* d_tab = (float*)alloc((size_t)NLAY * TABN * NFT * sizeof(float));
    float* d_hw  = (float*)alloc((size_t)NN * NFT * sizeof(float));
    float* d_m   = (float*)alloc((size_t)NN * NFT * sizeof(float));
    (void)ws_size; (void)in_sizes; (void)n_in; (void)out_size;

    find_ne<<<1, 1, 0, stream>>>(mask, d_ne);
    build_rowptr<<<(NN + 1 + 255) / 256, 256, 0, stream>>>(ei + EE, d_ne, d_rp);
    edge_geom<<<(EE + 255) / 256, 256, 0, stream>>>(ei, pos, mask, d_de, d_ce);
    tab_kernel<<<NLAY * TABN / 8, 256, 0, stream>>>(w1, b1, w2, b2, d_tab);
    init_h<<<NN * 32 / 256, 256, 0, stream>>>(z, (const float4*)emb, (float4*)h);

    const size_t lds_bytes = (4096 + 16384 + 8192 + 2048 + 128 + 128) * sizeof(float);
    for (int l = 0; l < NLAY; ++l) {
        hw_kernel<<<NN / 8, 256, 0, stream>>>(h, l1w + (size_t)l * HIDN * NFT, d_hw);
        edge_agg<<<NN / 8, 256, 0, stream>>>(d_rp, ei, d_de, d_ce,
                                             d_tab + (size_t)l * TABN * NFT, d_hw, d_m);
        node_update<<<NN / 64, 512, lds_bytes, stream>>>(
            d_m, l2w + (size_t)l * NFT * HIDN, l2b + (size_t)l * HIDN,
            lww + (size_t)l * HIDN * HIDN, lbb + (size_t)l * HIDN, h);
    }
}